// Round 13
// baseline (283.732 us; speedup 1.0000x reference)
//
#include <hip/hip_runtime.h>
#include <hip/hip_bf16.h>
#include <math.h>

#define N_TOK 32768
#define LC 16
#define NCHUNK (N_TOK / LC)    // 2048
#define NSEG 64
#define SEGLEN (NCHUNK / NSEG) // 32
#define CXT 16                 // tokens per k_cxd block == LC
#define NCXB (N_TOK / CXT)     // 2048 conv blocks; blocks >= NCXB do gather
#define XPAD 264               // padded LDS row stride (bf16): 132 dwords == 4 mod 32

typedef short short8 __attribute__((ext_vector_type(8)));   // 8 bf16 (4 VGPRs)
typedef float f32x4 __attribute__((ext_vector_type(4)));

__device__ __forceinline__ float siluf_(float v){ return v / (1.f + __expf(-v)); }
__device__ __forceinline__ float softplusf_(float v){ return v > 20.f ? v : __logf(1.f + __expf(v)); }

__device__ __forceinline__ unsigned f2bfu(float f){
  __hip_bfloat16 h = __float2bfloat16(f);
  return (unsigned)*(unsigned short*)&h;
}
__device__ __forceinline__ float bfu2f(unsigned short u){
  __hip_bfloat16 h; *(unsigned short*)&h = u; return __bfloat162float(h);
}

__device__ __forceinline__ float waveRed64(float v){
  #pragma unroll
  for (int m = 1; m < 64; m <<= 1) v += __shfl_xor(v, m);
  return v;
}

// pw[s] = w^(s+1), 15 muls, depth 4
__device__ __forceinline__ void pow_chain(float w, float pw[16]){
  pw[0]=w; pw[1]=w*w; pw[2]=pw[1]*w; pw[3]=pw[1]*pw[1];
  pw[4]=pw[3]*pw[0]; pw[5]=pw[3]*pw[1]; pw[6]=pw[3]*pw[2]; pw[7]=pw[3]*pw[3];
  pw[8]=pw[7]*pw[0]; pw[9]=pw[7]*pw[1]; pw[10]=pw[7]*pw[2]; pw[11]=pw[7]*pw[3];
  pw[12]=pw[7]*pw[4]; pw[13]=pw[7]*pw[5]; pw[14]=pw[7]*pw[6]; pw[15]=pw[7]*pw[7];
}

__device__ __forceinline__ bool check_intA(const float aS[16]){
  bool ok = true;
  #pragma unroll
  for (int s=0;s<16;s++){
    float tgt = (float)(s+1);
    if (fabsf(-aS[s] - tgt) > 1e-4f*tgt) ok = false;
  }
  return ok;
}

// ---------- K_front: rmsnorm->a0 (blocks 0..8191) AND all weight converts (8192..8815) ----------
__global__ void __launch_bounds__(256) k_front(const float* __restrict__ feat,
                        const float* __restrict__ rmsw,
                        unsigned* __restrict__ a0u,
                        const float* __restrict__ ipw, const float* __restrict__ opw,
                        const float* __restrict__ w1, const float* __restrict__ w2,
                        const float* __restrict__ xpw,
                        __hip_bfloat16* __restrict__ ipwt, __hip_bfloat16* __restrict__ opwt,
                        __hip_bfloat16* __restrict__ w1t, __hip_bfloat16* __restrict__ w2t,
                        __hip_bfloat16* __restrict__ xpwt){
  int bid = blockIdx.x;
  if (bid >= 8192){
    int e = (bid-8192)*256 + threadIdx.x;
    if (e < 65536){ int n=e>>7, k=e&127; ipwt[e]=__float2bfloat16(ipw[k*512+n]); }
    else if (e < 98304){ int f=e-65536; int n=f>>8, k=f&255; opwt[f]=__float2bfloat16(opw[k*128+n]); }
    else if (e < 131072){ int f=e-98304; int n=f>>8, k=f&255; w1t[f]=__float2bfloat16(w1[k*128+n]); }
    else if (e < 147456){ int f=e-131072; int n=f>>7, k=f&127; w2t[f]=__float2bfloat16(w2[k*128+n]); }
    else if (e < 159744){ int f=e-147456; int n=f>>8, k=f&255;
                          xpwt[f]=(n<40)?__float2bfloat16(xpw[k*40+n]):__float2bfloat16(0.f); }
    return;
  }
  int row = bid*4 + (threadIdx.x>>6);
  int lane = threadIdx.x & 63;
  float2 f2 = ((const float2*)feat)[row*64 + lane];
  float ss = waveRed64(f2.x*f2.x + f2.y*f2.y);
  float is0 = rsqrtf(ss * (1.f/128.f) + 1e-5f);
  float2 w = ((const float2*)rmsw)[lane];
  a0u[row*64 + lane] = f2bfu(f2.x*is0*w.x) | (f2bfu(f2.y*is0*w.y) << 16);
}

// ---------- in_proj MFMA GEMM (operand-swapped): 8B packed stores ----------
template<int WM16, int WN16>
__global__ __launch_bounds__(256) void k_mfma(const __hip_bfloat16* __restrict__ A,
      const __hip_bfloat16* __restrict__ Wt, int K,
      __hip_bfloat16* __restrict__ out0b, __hip_bfloat16* __restrict__ out1){
  int tid = threadIdx.x;
  int wave = tid>>6, lane = tid&63;
  int wm = wave>>1, wn = wave&1;
  int lane16 = lane&15, quad = lane>>4;
  int m_w = blockIdx.x*(2*WM16*16) + wm*(WM16*16);
  int n_w = blockIdx.y*(2*WN16*16) + wn*(WN16*16);
  f32x4 acc[WM16][WN16];
  #pragma unroll
  for (int i=0;i<WM16;i++)
    #pragma unroll
    for (int j=0;j<WN16;j++) acc[i][j] = (f32x4){0.f,0.f,0.f,0.f};
  const __hip_bfloat16* Ab = A  + (size_t)(m_w + lane16)*K + quad*8;
  const __hip_bfloat16* Bb = Wt + (size_t)(n_w + lane16)*K + quad*8;
  #pragma unroll 4
  for (int kk=0; kk<K; kk+=32){
    short8 a[WM16], b[WN16];
    #pragma unroll
    for (int i=0;i<WM16;i++) a[i] = *(const short8*)(Ab + (size_t)i*16*K + kk);
    #pragma unroll
    for (int j=0;j<WN16;j++) b[j] = *(const short8*)(Bb + (size_t)j*16*K + kk);
    #pragma unroll
    for (int i=0;i<WM16;i++)
      #pragma unroll
      for (int j=0;j<WN16;j++)
        acc[i][j] = __builtin_amdgcn_mfma_f32_16x16x32_bf16(b[j], a[i], acc[i][j], 0, 0, 0);
  }
  #pragma unroll
  for (int i=0;i<WM16;i++){
    int m = m_w + i*16 + lane16;
    #pragma unroll
    for (int j=0;j<WN16;j++){
      int n0 = n_w + j*16 + quad*4;
      if (n0 < 256){
        unsigned u0 = f2bfu(acc[i][j][0]) | (f2bfu(acc[i][j][1]) << 16);
        unsigned u1 = f2bfu(acc[i][j][2]) | (f2bfu(acc[i][j][3]) << 16);
        *(uint2*)(out0b + (size_t)m*256 + n0) = make_uint2(u0, u1);
      } else {
        unsigned u0 = f2bfu(siluf_(acc[i][j][0])) | (f2bfu(siluf_(acc[i][j][1])) << 16);
        unsigned u1 = f2bfu(siluf_(acc[i][j][2])) | (f2bfu(siluf_(acc[i][j][3])) << 16);
        *(uint2*)(out1 + (size_t)m*256 + (n0-256)) = make_uint2(u0, u1);
      }
    }
  }
}

// ---------- K_cxd: conv+silu+xproj+delta+SCAN1 (blocks < NCXB) AND gather+LN (>= NCXB) ----------
// CXT == LC: each conv block IS one scan chunk; scan pass 1 fused (B kept in LDS, delta
// consumed in-iteration), writing Hc + dsum directly. k_scan1 kernel eliminated.
__global__ __launch_bounds__(256) void k_cxd(
      const __hip_bfloat16* __restrict__ bxb,   // [N,256] pre-conv x
      const __hip_bfloat16* __restrict__ xpwt,  // [48,256] x_proj^T (zero-padded)
      const float* __restrict__ cw, const float* __restrict__ cb,
      const float* __restrict__ dtw, const float* __restrict__ dtb,
      const float* __restrict__ A_log,
      unsigned* __restrict__ dxb,               // [N,256] (delta | x) bf16 pair
      float* __restrict__ Bm, float* __restrict__ Cm,
      float* __restrict__ dsum_o, __hip_bfloat16* __restrict__ Hc,
      const float* __restrict__ feat, const int* __restrict__ ridx,
      const float* __restrict__ gd, const float* __restrict__ g,
      const float* __restrict__ b, unsigned* __restrict__ catB){
  int tid = threadIdx.x;
  int bid = blockIdx.x;

  if (bid >= NCXB){
    // ---- gather + LN -> catB (low-VGPR dependent-load form; occupancy-optimal) ----
    int row = (bid - NCXB)*4 + (tid>>6);
    int lane = tid & 63;
    float ax=0.f, ay=0.f;
    #pragma unroll 4
    for (int k=0;k<16;k++){
      int idx = ridx[row*16+k];
      float ww = gd[row*16+k];
      float2 f = ((const float2*)feat)[idx*64 + lane];
      ax += ww*f.x; ay += ww*f.y;
    }
    float m = waveRed64(ax+ay) * (1.f/128.f);
    float dx = ax-m, dy = ay-m;
    float var = waveRed64(dx*dx+dy*dy) * (1.f/128.f);
    float is = rsqrtf(var + 1e-5f);
    float2 gg = ((const float2*)g)[lane];
    float2 bb = ((const float2*)b)[lane];
    float ox = dx*is*gg.x + bb.x, oy = dy*is*gg.y + bb.y;
    catB[row*64 + lane] = f2bfu(ox) | (f2bfu(oy) << 16);
    return;
  }

  __shared__ __align__(16) __hip_bfloat16 Xs[CXT][XPAD];  // 8.4 KB
  __shared__ __align__(16) float DT[CXT][8];              // 0.5 KB
  __shared__ __align__(16) float Bs[CXT][16];             // 1 KB (B tile for fused scan)
  int wave = tid>>6, lane = tid&63;
  int lane16 = lane&15, quad = lane>>4;
  int r0 = bid*CXT;

  // ---- causal depthwise conv + silu direct from global (coalesced rows), write Xs once ----
  {
    int d = tid;
    float cw0=cw[d*4], cw1=cw[d*4+1], cw2=cw[d*4+2], cw3=cw[d*4+3], cbb=cb[d];
    float a_0 = (r0 >= 3) ? __bfloat162float(bxb[(size_t)(r0-3)*256 + d]) : 0.f;
    float a_1 = (r0 >= 2) ? __bfloat162float(bxb[(size_t)(r0-2)*256 + d]) : 0.f;
    float a_2 = (r0 >= 1) ? __bfloat162float(bxb[(size_t)(r0-1)*256 + d]) : 0.f;
    #pragma unroll 4
    for (int t=0;t<CXT;t++){
      float a_3 = __bfloat162float(bxb[(size_t)(r0+t)*256 + d]);
      float xc = siluf_(cbb + cw0*a_0 + cw1*a_1 + cw2*a_2 + cw3*a_3);
      Xs[t][d] = __float2bfloat16(xc);
      a_0=a_1; a_1=a_2; a_2=a_3;
    }
  }
  __syncthreads();

  // ---- xproj MFMA from LDS: dbc[16,48] = xc @ xpwt^T (waves 0..2, one n-tile each) ----
  if (wave < 3){
    f32x4 acc3 = (f32x4){0.f,0.f,0.f,0.f};
    const __hip_bfloat16* Arow = &Xs[lane16][0] + quad*8;
    const __hip_bfloat16* Bb = xpwt + (size_t)(wave*16 + lane16)*256 + quad*8;
    #pragma unroll
    for (int kk=0; kk<256; kk+=32){
      short8 a  = *(const short8*)(Arow + kk);
      short8 bfr = *(const short8*)(Bb + kk);
      acc3 = __builtin_amdgcn_mfma_f32_16x16x32_bf16(a, bfr, acc3, 0, 0, 0);
    }
    int n = wave*16 + lane16;
    #pragma unroll
    for (int r=0;r<4;r++){
      int m = quad*4 + r;
      float v = acc3[r];
      if (n < 8)       DT[m][n] = v;
      else if (n < 24){ Bs[m][n-8] = v; Bm[(size_t)(r0+m)*16 + (n-8)] = v; }
      else if (n < 40) Cm[(size_t)(r0+m)*16 + (n-24)] = v;
    }
  }
  __syncthreads();

  // ---- fused delta + scan pass 1 (delta consumed in-iteration; B from LDS) ----
  {
    int d = tid;
    float w8[8];
    #pragma unroll
    for (int j=0;j<8;j++) w8[j] = dtw[j*256+d];
    float dbias = dtb[d];
    float aS[16];
    #pragma unroll
    for (int s=0;s<16;s++) aS[s] = -__expf(A_log[d*16+s]);
    bool fastA = check_intA(aS);
    float h[16] = {};
    float dsum = 0.f;
    if (fastA){
      #pragma unroll 4
      for (int t=0;t<CXT;t++){
        const float4* T = (const float4*)&DT[t][0];   // wave-uniform broadcast
        float4 u = T[0], v = T[1];
        float acc = dbias
          + u.x*w8[0] + u.y*w8[1] + u.z*w8[2] + u.w*w8[3]
          + v.x*w8[4] + v.y*w8[5] + v.z*w8[6] + v.w*w8[7];
        float dv = softplusf_(acc);
        unsigned xu = *(const unsigned short*)&Xs[t][d];
        dxb[(size_t)(r0+t)*256 + d] = f2bfu(dv) | (xu << 16);
        float xv = bfu2f((unsigned short)xu);
        dsum += dv;
        float dx_ = dv*xv;
        const float4* Bp = (const float4*)&Bs[t][0];  // broadcast
        float4 b0=Bp[0], b1=Bp[1], b2=Bp[2], b3=Bp[3];
        float bl[16] = {b0.x,b0.y,b0.z,b0.w, b1.x,b1.y,b1.z,b1.w,
                        b2.x,b2.y,b2.z,b2.w, b3.x,b3.y,b3.z,b3.w};
        float w[16]; pow_chain(__expf(-dv), w);
        #pragma unroll
        for (int s=0;s<16;s++) h[s] = w[s]*h[s] + dx_*bl[s];
      }
    } else {
      #pragma unroll 4
      for (int t=0;t<CXT;t++){
        const float4* T = (const float4*)&DT[t][0];
        float4 u = T[0], v = T[1];
        float acc = dbias
          + u.x*w8[0] + u.y*w8[1] + u.z*w8[2] + u.w*w8[3]
          + v.x*w8[4] + v.y*w8[5] + v.z*w8[6] + v.w*w8[7];
        float dv = softplusf_(acc);
        unsigned xu = *(const unsigned short*)&Xs[t][d];
        dxb[(size_t)(r0+t)*256 + d] = f2bfu(dv) | (xu << 16);
        float xv = bfu2f((unsigned short)xu);
        dsum += dv;
        float dx_ = dv*xv;
        const float4* Bp = (const float4*)&Bs[t][0];
        float4 b0=Bp[0], b1=Bp[1], b2=Bp[2], b3=Bp[3];
        float bl[16] = {b0.x,b0.y,b0.z,b0.w, b1.x,b1.y,b1.z,b1.w,
                        b2.x,b2.y,b2.z,b2.w, b3.x,b3.y,b3.z,b3.w};
        #pragma unroll
        for (int s=0;s<16;s++) h[s] = __expf(dv*aS[s])*h[s] + dx_*bl[s];
      }
    }
    dsum_o[(size_t)bid*256 + d] = dsum;
    unsigned uu[8];
    #pragma unroll
    for (int q=0;q<8;q++) uu[q] = f2bfu(h[2*q]) | (f2bfu(h[2*q+1]) << 16);
    uint4* Hd = (uint4*)(Hc + (size_t)bid*4096 + (size_t)d*16);
    Hd[0] = make_uint4(uu[0],uu[1],uu[2],uu[3]);
    Hd[1] = make_uint4(uu[4],uu[5],uu[6],uu[7]);
  }
}

// ---------- K6a: within-segment prefix (in place on Hc; dsum prefix to dsum_pre) ----------
__global__ __launch_bounds__(256) void k_carry_a(const float* __restrict__ dsum,
      __hip_bfloat16* __restrict__ Hc, const float* __restrict__ A_log,
      float* __restrict__ dsum_pre, float* __restrict__ segsum, float* __restrict__ Hagg){
  int seg = blockIdx.x;
  int ch  = blockIdx.y*256 + threadIdx.x;
  int d = ch>>4, s = ch&15;
  float aSv = -__expf(A_log[ch]);
  float dpre = 0.f, c = 0.f;
  int g0 = seg*SEGLEN;
  #pragma unroll 4
  for (int i=0;i<SEGLEN;i++){
    int g = g0+i;
    float ds = dsum[(size_t)g*256 + d];
    size_t a = (size_t)g*4096 + ch;
    float hh = __bfloat162float(Hc[a]);
    float p = __expf(ds*aSv);
    if (s==0) dsum_pre[(size_t)g*256 + d] = dpre;
    Hc[a] = __float2bfloat16(c);
    dpre += ds;
    c = p*c + hh;
  }
  if (s==0) segsum[seg*256 + d] = dpre;
  Hagg[(size_t)seg*4096 + ch] = c;
}

// ---------- K6b: scan over segment aggregates -> Cseg ----------
__global__ __launch_bounds__(256) void k_carry_b(const float* __restrict__ segsum,
      const float* __restrict__ Hagg, const float* __restrict__ A_log,
      float* __restrict__ Cseg){
  int ch = blockIdx.x*256 + threadIdx.x;
  int d = ch>>4;
  float aSv = -__expf(A_log[ch]);
  float c = 0.f;
  #pragma unroll 8
  for (int s=0;s<NSEG;s++){
    Cseg[(size_t)s*4096 + ch] = c;
    c = __expf(segsum[s*256 + d]*aSv)*c + Hagg[(size_t)s*4096 + ch];
  }
}

// ---------- K7: scan pass 2 — 256-thread block per chunk (LC=16), gated y ----------
__global__ __launch_bounds__(256) void k_scan2(const unsigned* __restrict__ dxb,
      const __hip_bfloat16* __restrict__ zb, const float* __restrict__ Bm,
      const float* __restrict__ Cm, const float* __restrict__ A_log,
      const float* __restrict__ Dp, const float* __restrict__ dsum_pre,
      const __hip_bfloat16* __restrict__ Hc, const float* __restrict__ Cseg,
      __hip_bfloat16* __restrict__ yb){
  __shared__ float Bl[LC][16];
  __shared__ float Cl[LC][16];
  int g = blockIdx.x;
  int tid = threadIdx.x;
  int d = tid;
  int t0 = g*LC;
  if (tid < 64) ((float4*)&Bl[0][0])[tid] = ((const float4*)(Bm + (size_t)t0*16))[tid];
  else if (tid < 128) ((float4*)&Cl[0][0])[tid-64] = ((const float4*)(Cm + (size_t)t0*16))[tid-64];
  __syncthreads();
  int seg = g / SEGLEN;
  float aS[16];
  #pragma unroll
  for (int s=0;s<16;s++) aS[s] = -__expf(A_log[d*16+s]);
  bool fastA = check_intA(aS);
  float h[16];
  {
    float dpre = dsum_pre[(size_t)g*256 + d];
    const uint4* hp = (const uint4*)(Hc + (size_t)g*4096 + (size_t)d*16);
    uint4 H0 = hp[0], H1 = hp[1];
    unsigned hu[8] = {H0.x,H0.y,H0.z,H0.w, H1.x,H1.y,H1.z,H1.w};
    const float4* cs = (const float4*)(Cseg + (size_t)seg*4096 + (size_t)d*16);
    float ws[16];
    if (fastA){
      pow_chain(__expf(-dpre), ws);
    } else {
      #pragma unroll
      for (int s=0;s<16;s++) ws[s] = __expf(dpre*aS[s]);
    }
    #pragma unroll
    for (int q=0;q<4;q++){
      float4 C = cs[q];
      h[q*4+0] = ws[q*4+0]*C.x + bfu2f((unsigned short)(hu[q*2]   & 0xffff));
      h[q*4+1] = ws[q*4+1]*C.y + bfu2f((unsigned short)(hu[q*2]   >> 16));
      h[q*4+2] = ws[q*4+2]*C.z + bfu2f((unsigned short)(hu[q*2+1] & 0xffff));
      h[q*4+3] = ws[q*4+3]*C.w + bfu2f((unsigned short)(hu[q*2+1] >> 16));
    }
  }
  float dpar = Dp[d];
  if (fastA){
    #pragma unroll 4
    for (int t=0;t<LC;t++){
      unsigned u = dxb[(size_t)(t0+t)*256 + d];
      float dv = bfu2f((unsigned short)(u & 0xffff));
      float xv = bfu2f((unsigned short)(u >> 16));
      float zv = __bfloat162float(zb[(size_t)(t0+t)*256 + d]);
      const float4* Bp = (const float4*)&Bl[t][0];
      const float4* Cp = (const float4*)&Cl[t][0];
      float4 b0=Bp[0], b1=Bp[1], b2=Bp[2], b3=Bp[3];
      float4 c0=Cp[0], c1=Cp[1], c2=Cp[2], c3=Cp[3];
      float bl[16] = {b0.x,b0.y,b0.z,b0.w, b1.x,b1.y,b1.z,b1.w,
                      b2.x,b2.y,b2.z,b2.w, b3.x,b3.y,b3.z,b3.w};
      float cl[16] = {c0.x,c0.y,c0.z,c0.w, c1.x,c1.y,c1.z,c1.w,
                      c2.x,c2.y,c2.z,c2.w, c3.x,c3.y,c3.z,c3.w};
      float dx_ = dv*xv;
      float w[16]; pow_chain(__expf(-dv), w);
      float yv = 0.f;
      #pragma unroll
      for (int s=0;s<16;s++){
        h[s] = w[s]*h[s] + dx_*bl[s];
        yv += h[s]*cl[s];
      }
      yb[(size_t)(t0+t)*256 + d] = __float2bfloat16((yv + dpar*xv)*zv);
    }
  } else {
    #pragma unroll 4
    for (int t=0;t<LC;t++){
      unsigned u = dxb[(size_t)(t0+t)*256 + d];
      float dv = bfu2f((unsigned short)(u & 0xffff));
      float xv = bfu2f((unsigned short)(u >> 16));
      float zv = __bfloat162float(zb[(size_t)(t0+t)*256 + d]);
      const float4* Bp = (const float4*)&Bl[t][0];
      const float4* Cp = (const float4*)&Cl[t][0];
      float4 b0=Bp[0], b1=Bp[1], b2=Bp[2], b3=Bp[3];
      float4 c0=Cp[0], c1=Cp[1], c2=Cp[2], c3=Cp[3];
      float bl[16] = {b0.x,b0.y,b0.z,b0.w, b1.x,b1.y,b1.z,b1.w,
                      b2.x,b2.y,b2.z,b2.w, b3.x,b3.y,b3.z,b3.w};
      float cl[16] = {c0.x,c0.y,c0.z,c0.w, c1.x,c1.y,c1.z,c1.w,
                      c2.x,c2.y,c2.z,c2.w, c3.x,c3.y,c3.z,c3.w};
      float dx_ = dv*xv;
      float yv = 0.f;
      #pragma unroll
      for (int s=0;s<16;s++){
        h[s] = __expf(dv*aS[s])*h[s] + dx_*bl[s];
        yv += h[s]*cl[s];
      }
      yb[(size_t)(t0+t)*256 + d] = __float2bfloat16((yv + dpar*xv)*zv);
    }
  }
}

// ---------- K_tail: out_proj+LN -> mlp1+LN+relu -> mlp2, all in one block (64 rows) ----------
__global__ __launch_bounds__(256) void k_tail(const __hip_bfloat16* __restrict__ yb,
      const __hip_bfloat16* __restrict__ opwt, const float* __restrict__ feat,
      const float* __restrict__ lng, const float* __restrict__ lnb,
      const unsigned* __restrict__ catB,
      const __hip_bfloat16* __restrict__ w1t, const float* __restrict__ b1,
      const float* __restrict__ lag, const float* __restrict__ lab,
      const __hip_bfloat16* __restrict__ w2t, const float* __restrict__ b2,
      float* __restrict__ out){
  __shared__ __align__(16) float Ls[64][132];
  __shared__ __align__(16) unsigned Cu[64][132];  // bf16-pair tile: cat (256 wide) then h1 (128 wide)
  int tid = threadIdx.x;
  int wave = tid>>6, lane = tid&63;
  int wm = wave>>1, wn = wave&1;
  int lane16 = lane&15, quad = lane>>4;
  int r0 = blockIdx.x*64;

  // stage gathered half of cat into Cu cols 64..127 (bf16 cols 128..255)
  #pragma unroll
  for (int i=0;i<16;i++){
    int idx = i*256 + tid;
    int row = idx>>6, c = idx&63;
    Cu[row][64+c] = catB[(size_t)(r0+row)*64 + c];
  }

  f32x4 acc[2][4];
  // ---- GEMM1: yb[64x256] @ opwt[128x256]^T, + feat resid -> Ls ----
  #pragma unroll
  for (int i=0;i<2;i++)
    #pragma unroll
    for (int j=0;j<4;j++) acc[i][j] = (f32x4){0.f,0.f,0.f,0.f};
  {
    const __hip_bfloat16* Ab = yb   + (size_t)(r0 + wm*32 + lane16)*256 + quad*8;
    const __hip_bfloat16* Bb = opwt + (size_t)(wn*64 + lane16)*256 + quad*8;
    #pragma unroll 2
    for (int kk=0; kk<256; kk+=32){
      short8 a[2], bf[4];
      #pragma unroll
      for (int i=0;i<2;i++) a[i] = *(const short8*)(Ab + (size_t)i*16*256 + kk);
      #pragma unroll
      for (int j=0;j<4;j++) bf[j] = *(const short8*)(Bb + (size_t)j*16*256 + kk);
      #pragma unroll
      for (int i=0;i<2;i++)
        #pragma unroll
        for (int j=0;j<4;j++)
          acc[i][j] = __builtin_amdgcn_mfma_f32_16x16x32_bf16(a[i], bf[j], acc[i][j], 0, 0, 0);
    }
  }
  #pragma unroll
  for (int i=0;i<2;i++)
    #pragma unroll
    for (int j=0;j<4;j++){
      int n = wn*64 + j*16 + lane16;
      #pragma unroll
      for (int r=0;r<4;r++){
        int m = wm*32 + i*16 + quad*4 + r;
        Ls[m][n] = acc[i][j][r] + feat[(size_t)(r0+m)*128 + n];
      }
    }
  __syncthreads();
  // ---- LN1 -> Cu cols 0..63 (bf16 cols 0..127) ----
  {
    float2 gv = ((const float2*)lng)[lane];
    float2 bv = ((const float2*)lnb)[lane];
    #pragma unroll 4
    for (int rr=0; rr<16; rr++){
      int row = wave*16 + rr;
      float2 v = *(const float2*)&Ls[row][2*lane];
      float mm = waveRed64(v.x+v.y) * (1.f/128.f);
      float dx = v.x-mm, dy = v.y-mm;
      float var = waveRed64(dx*dx+dy*dy) * (1.f/128.f);
      float is = rsqrtf(var + 1e-5f);
      Cu[row][lane] = f2bfu(dx*is*gv.x + bv.x) | (f2bfu(dy*is*gv.y + bv.y) << 16);
    }
  }
  __syncthreads();
  // ---- GEMM2: cat[64x256] (LDS) @ w1t[128x256]^T, + b1 -> Ls ----
  #pragma unroll
  for (int i=0;i<2;i++)
    #pragma unroll
    for (int j=0;j<4;j++) acc[i][j] = (f32x4){0.f,0.f,0.f,0.f};
  {
    const __hip_bfloat16* Bb = w1t + (size_t)(wn*64 + lane16)*256 + quad*8;
    #pragma unroll 2
    for (int kk=0; kk<256; kk+=32){
      short8 a[2], bf[4];
      #pragma unroll
      for (int i=0;i<2;i++)
        a[i] = *(const short8*)(&Cu[wm*32 + i*16 + lane16][0] + (kk>>1) + quad*4);
      #pragma unroll
      for (int j=0;j<4;j++) bf[j] = *(const short8*)(Bb + (size_t)j*16*256 + kk);
      #pragma unroll
      for (int i=0;i<2;i++)
        #pragma unroll
        for (int j=0;j<4;j++)
          acc[i][j] = __builtin_amdgcn_mfma_f32_16x16x32_bf16(a[i], bf[j], acc[i][j], 0, 0, 0);
    }
  }
  #pragma unroll
  for (int i=0;i<2;i++)
    #pragma unroll
    for (int j=0;j<4;j++){
      int n = wn*64 + j*16 + lane16;
      float bv1 = b1[n];
      #pragma unroll
      for (int r=0;r<4;r++){
        int m = wm*32 + i*16 + quad*4 + r;
        Ls[m][n] = acc[i][j][r] + bv1;
      }
    }
  __syncthreads();
  // ---- LN2 + relu -> Cu cols 0..63 (h1, bf16 cols 0..127) ----
  {
    float2 gv = ((const float2*)lag)[lane];
    float2 bv = ((const float2*)lab)[lane];
    #pragma unroll 4
    for (int rr=0; rr<16; rr++){
      int row = wave*16 + rr;
      float2 v = *(const float2*)&Ls[row][2*lane];
      float mm = waveRed64(v.x+v.y) * (1.f/128.f);
      float dx = v.x-mm, dy = v.y-mm;
      float var = waveRed64(dx*dx+dy*dy) * (1.f/128.f);
      float is = rsqrtf(var + 1e-5f);
      float ox = fmaxf(dx*is*gv.x + bv.x, 0.f);
      float oy = fmaxf(dy*is*gv.y + bv.y, 0.f);
      Cu[row][lane] = f2bfu(ox) | (f2bfu(oy) << 16);
    }
  }
  __syncthreads();
  // ---- GEMM3 (operand-swapped): h1[64x128] (LDS) @ w2t[128x128]^T, + b2 -> out (float4) ----
  #pragma unroll
  for (int i=0;i<2;i++)
    #pragma unroll
    for (int j=0;j<4;j++) acc[i][j] = (f32x4){0.f,0.f,0.f,0.f};
  {
    const __hip_bfloat16* Bb = w2t + (size_t)(wn*64 + lane16)*128 + quad*8;
    #pragma unroll
    for (int kk=0; kk<128; kk+=32){
      short8 a[2], bf[4];
      #pragma unroll
      for (int i=0;i<2;i++)
        a[i] = *(const short8*)(&Cu[wm*32 + i*16 + lane16][0] + (kk>>1) + quad*4);
      #pragma unroll
      for (int j=0;j<4;j++) bf[j] = *(const short8*)(Bb + (size_t)j*16*128 + kk);
      #pragma unroll
      for (int i=0;i<2;i++)
        #pragma unroll
        for (int j=0;j<4;j++)
          acc[i][j] = __builtin_amdgcn_mfma_f32_16x16x32_bf16(bf[j], a[i], acc[i][j], 0, 0, 0);
    }
  }
  #pragma unroll
  for (int i=0;i<2;i++){
    int m = wm*32 + i*16 + lane16;
    #pragma unroll
    for (int j=0;j<4;j++){
      int n0 = wn*64 + j*16 + quad*4;
      float4 o;
      o.x = acc[i][j][0] + b2[n0+0];
      o.y = acc[i][j][1] + b2[n0+1];
      o.z = acc[i][j][2] + b2[n0+2];
      o.w = acc[i][j][3] + b2[n0+3];
      *(float4*)(out + (size_t)(r0+m)*128 + n0) = o;
    }
  }
}

extern "C" void kernel_launch(void* const* d_in, const int* in_sizes, int n_in,
                              void* d_out, int out_size, void* d_ws, size_t ws_size,
                              hipStream_t stream){
  const float* feat = (const float*)d_in[0];
  const int*   ridx = (const int*)d_in[2];
  const float* gd   = (const float*)d_in[3];
  const float* ipw  = (const float*)d_in[5];
  const float* cw   = (const float*)d_in[6];
  const float* cb   = (const float*)d_in[7];
  const float* xpw  = (const float*)d_in[8];
  const float* dtw  = (const float*)d_in[9];
  const float* dtb  = (const float*)d_in[10];
  const float* alog = (const float*)d_in[11];
  const float* dpar = (const float*)d_in[12];
  const float* opw  = (const float*)d_in[13];
  const float* rmsw = (const float*)d_in[14];
  const float* lng  = (const float*)d_in[15];
  const float* lnb  = (const float*)d_in[16];
  const float* w1   = (const float*)d_in[17];
  const float* b1   = (const float*)d_in[18];
  const float* lag  = (const float*)d_in[19];
  const float* lab  = (const float*)d_in[20];
  const float* w2   = (const float*)d_in[21];
  const float* b2   = (const float*)d_in[22];
  float* out = (float*)d_out;

  char* p = (char*)d_ws;
  __hip_bfloat16* bxb  = (__hip_bfloat16*)p; p += (size_t)N_TOK*256*2;   // 16MB pre-conv x
  __hip_bfloat16* zb   = (__hip_bfloat16*)p; p += (size_t)N_TOK*256*2;   // 16MB silu(z)
  unsigned* dxb        = (unsigned*)p;       p += (size_t)N_TOK*256*4;   // 32MB (delta|x) packed
  unsigned* catB       = (unsigned*)p;       p += (size_t)N_TOK*64*4;    // 8MB gathered+LN half
  __hip_bfloat16* yb   = (__hip_bfloat16*)p; p += (size_t)N_TOK*256*2;   // 16MB gated y; a0 early
  float* Bm   = (float*)p; p += (size_t)N_TOK*16*4;                      // 2MB
  float* Cm   = (float*)p; p += (size_t)N_TOK*16*4;                      // 2MB
  __hip_bfloat16* Hc = (__hip_bfloat16*)p; p += (size_t)NCHUNK*4096*2;   // 16MB (bf16)
  float* dsum = (float*)p; p += (size_t)NCHUNK*256*4;                    // 2MB
  float* dpre = (float*)p; p += (size_t)NCHUNK*256*4;                    // 2MB
  float* segs = (float*)p; p += (size_t)NSEG*256*4;                      // 64KB
  float* Hagg = (float*)p; p += (size_t)NSEG*4096*4;                     // 1MB
  float* Cseg = (float*)p; p += (size_t)NSEG*4096*4;                     // 1MB
  __hip_bfloat16* ipwt = (__hip_bfloat16*)p; p += 512*128*2;
  __hip_bfloat16* opwt = (__hip_bfloat16*)p; p += 128*256*2;
  __hip_bfloat16* w1t  = (__hip_bfloat16*)p; p += 128*256*2;
  __hip_bfloat16* w2t  = (__hip_bfloat16*)p; p += 128*128*2;
  __hip_bfloat16* xpwt = (__hip_bfloat16*)p; p += 48*256*2;
  __hip_bfloat16* a0 = yb;                     // N*128 bf16, dead before scan2 writes yb

  hipLaunchKernelGGL(k_front, dim3(8192+624), dim3(256), 0, stream,
                     feat, rmsw, (unsigned*)a0,
                     ipw, opw, w1, w2, xpw, ipwt, opwt, w1t, w2t, xpwt);
  hipLaunchKernelGGL((k_mfma<4,4>), dim3(N_TOK/128, 4), dim3(256), 0, stream,
                     a0, ipwt, 128, bxb, zb);
  hipLaunchKernelGGL(k_cxd, dim3(NCXB + 8192), dim3(256), 0, stream,
                     bxb, xpwt, cw, cb, dtw, dtb, alog, dxb, Bm, Cm, dsum, Hc,
                     feat, ridx, gd, lng, lnb, catB);
  hipLaunchKernelGGL(k_carry_a, dim3(NSEG, 16), dim3(256), 0, stream,
                     dsum, Hc, alog, dpre, segs, Hagg);
  hipLaunchKernelGGL(k_carry_b, dim3(16), dim3(256), 0, stream, segs, Hagg, alog, Cseg);
  hipLaunchKernelGGL(k_scan2, dim3(NCHUNK), dim3(256), 0, stream,
                     dxb, zb, Bm, Cm, alog, dpar, dpre, Hc, Cseg, yb);
  hipLaunchKernelGGL(k_tail, dim3(N_TOK/64), dim3(256), 0, stream,
                     yb, opwt, feat, lng, lnb, catB, w1t, b1, lag, lab, w2t, b2, out);
}

// Round 14
// 265.558 us; speedup vs baseline: 1.0684x; 1.0684x over previous
//
#include <hip/hip_runtime.h>
#include <hip/hip_bf16.h>
#include <math.h>

#define N_TOK 32768
#define LC 32
#define NCHUNK (N_TOK / LC)    // 1024
#define NSEG 64
#define SEGLEN (NCHUNK / NSEG) // 16
#define CXT 16                 // tokens per k_cxd block
#define NCXB (N_TOK / CXT)     // 2048 conv blocks; blocks >= NCXB do gather
#define XPAD 264               // padded LDS row stride (bf16): 132 dwords == 4 mod 32

typedef short short8 __attribute__((ext_vector_type(8)));   // 8 bf16 (4 VGPRs)
typedef float f32x4 __attribute__((ext_vector_type(4)));

__device__ __forceinline__ float siluf_(float v){ return v / (1.f + __expf(-v)); }
__device__ __forceinline__ float softplusf_(float v){ return v > 20.f ? v : __logf(1.f + __expf(v)); }

__device__ __forceinline__ unsigned f2bfu(float f){
  __hip_bfloat16 h = __float2bfloat16(f);
  return (unsigned)*(unsigned short*)&h;
}
__device__ __forceinline__ float bfu2f(unsigned short u){
  __hip_bfloat16 h; *(unsigned short*)&h = u; return __bfloat162float(h);
}

__device__ __forceinline__ float waveRed64(float v){
  #pragma unroll
  for (int m = 1; m < 64; m <<= 1) v += __shfl_xor(v, m);
  return v;
}

// pw[s] = w^(s+1), 15 muls, depth 4
__device__ __forceinline__ void pow_chain(float w, float pw[16]){
  pw[0]=w; pw[1]=w*w; pw[2]=pw[1]*w; pw[3]=pw[1]*pw[1];
  pw[4]=pw[3]*pw[0]; pw[5]=pw[3]*pw[1]; pw[6]=pw[3]*pw[2]; pw[7]=pw[3]*pw[3];
  pw[8]=pw[7]*pw[0]; pw[9]=pw[7]*pw[1]; pw[10]=pw[7]*pw[2]; pw[11]=pw[7]*pw[3];
  pw[12]=pw[7]*pw[4]; pw[13]=pw[7]*pw[5]; pw[14]=pw[7]*pw[6]; pw[15]=pw[7]*pw[7];
}

__device__ __forceinline__ bool check_intA(const float aS[16]){
  bool ok = true;
  #pragma unroll
  for (int s=0;s<16;s++){
    float tgt = (float)(s+1);
    if (fabsf(-aS[s] - tgt) > 1e-4f*tgt) ok = false;
  }
  return ok;
}

// ---------- K_front: rmsnorm->a0 + bf16 feat copy (blocks 0..8191) AND weight converts ----------
__global__ void __launch_bounds__(256) k_front(const float* __restrict__ feat,
                        const float* __restrict__ rmsw,
                        unsigned* __restrict__ a0u, unsigned* __restrict__ fb16u,
                        const float* __restrict__ ipw, const float* __restrict__ opw,
                        const float* __restrict__ w1, const float* __restrict__ w2,
                        const float* __restrict__ xpw,
                        __hip_bfloat16* __restrict__ ipwt, __hip_bfloat16* __restrict__ opwt,
                        __hip_bfloat16* __restrict__ w1t, __hip_bfloat16* __restrict__ w2t,
                        __hip_bfloat16* __restrict__ xpwt){
  int bid = blockIdx.x;
  if (bid >= 8192){
    int e = (bid-8192)*256 + threadIdx.x;
    if (e < 65536){ int n=e>>7, k=e&127; ipwt[e]=__float2bfloat16(ipw[k*512+n]); }
    else if (e < 98304){ int f=e-65536; int n=f>>8, k=f&255; opwt[f]=__float2bfloat16(opw[k*128+n]); }
    else if (e < 131072){ int f=e-98304; int n=f>>8, k=f&255; w1t[f]=__float2bfloat16(w1[k*128+n]); }
    else if (e < 147456){ int f=e-131072; int n=f>>7, k=f&127; w2t[f]=__float2bfloat16(w2[k*128+n]); }
    else if (e < 159744){ int f=e-147456; int n=f>>8, k=f&255;
                          xpwt[f]=(n<40)?__float2bfloat16(xpw[k*40+n]):__float2bfloat16(0.f); }
    return;
  }
  int row = bid*4 + (threadIdx.x>>6);
  int lane = threadIdx.x & 63;
  float2 f2 = ((const float2*)feat)[row*64 + lane];
  // side-product: bf16 copy of feat for the low-byte gather
  fb16u[row*64 + lane] = f2bfu(f2.x) | (f2bfu(f2.y) << 16);
  float ss = waveRed64(f2.x*f2.x + f2.y*f2.y);
  float is0 = rsqrtf(ss * (1.f/128.f) + 1e-5f);
  float2 w = ((const float2*)rmsw)[lane];
  a0u[row*64 + lane] = f2bfu(f2.x*is0*w.x) | (f2bfu(f2.y*is0*w.y) << 16);
}

// ---------- in_proj MFMA GEMM (operand-swapped): 8B packed stores ----------
template<int WM16, int WN16>
__global__ __launch_bounds__(256) void k_mfma(const __hip_bfloat16* __restrict__ A,
      const __hip_bfloat16* __restrict__ Wt, int K,
      __hip_bfloat16* __restrict__ out0b, __hip_bfloat16* __restrict__ out1){
  int tid = threadIdx.x;
  int wave = tid>>6, lane = tid&63;
  int wm = wave>>1, wn = wave&1;
  int lane16 = lane&15, quad = lane>>4;
  int m_w = blockIdx.x*(2*WM16*16) + wm*(WM16*16);
  int n_w = blockIdx.y*(2*WN16*16) + wn*(WN16*16);
  f32x4 acc[WM16][WN16];
  #pragma unroll
  for (int i=0;i<WM16;i++)
    #pragma unroll
    for (int j=0;j<WN16;j++) acc[i][j] = (f32x4){0.f,0.f,0.f,0.f};
  const __hip_bfloat16* Ab = A  + (size_t)(m_w + lane16)*K + quad*8;
  const __hip_bfloat16* Bb = Wt + (size_t)(n_w + lane16)*K + quad*8;
  #pragma unroll 4
  for (int kk=0; kk<K; kk+=32){
    short8 a[WM16], b[WN16];
    #pragma unroll
    for (int i=0;i<WM16;i++) a[i] = *(const short8*)(Ab + (size_t)i*16*K + kk);
    #pragma unroll
    for (int j=0;j<WN16;j++) b[j] = *(const short8*)(Bb + (size_t)j*16*K + kk);
    #pragma unroll
    for (int i=0;i<WM16;i++)
      #pragma unroll
      for (int j=0;j<WN16;j++)
        acc[i][j] = __builtin_amdgcn_mfma_f32_16x16x32_bf16(b[j], a[i], acc[i][j], 0, 0, 0);
  }
  #pragma unroll
  for (int i=0;i<WM16;i++){
    int m = m_w + i*16 + lane16;
    #pragma unroll
    for (int j=0;j<WN16;j++){
      int n0 = n_w + j*16 + quad*4;
      if (n0 < 256){
        unsigned u0 = f2bfu(acc[i][j][0]) | (f2bfu(acc[i][j][1]) << 16);
        unsigned u1 = f2bfu(acc[i][j][2]) | (f2bfu(acc[i][j][3]) << 16);
        *(uint2*)(out0b + (size_t)m*256 + n0) = make_uint2(u0, u1);
      } else {
        unsigned u0 = f2bfu(siluf_(acc[i][j][0])) | (f2bfu(siluf_(acc[i][j][1])) << 16);
        unsigned u1 = f2bfu(siluf_(acc[i][j][2])) | (f2bfu(siluf_(acc[i][j][3])) << 16);
        *(uint2*)(out1 + (size_t)m*256 + (n0-256)) = make_uint2(u0, u1);
      }
    }
  }
}

// ---------- K_cxd: conv+silu+xproj+delta (blocks < NCXB) AND gather+LN (blocks >= NCXB) ----------
__global__ __launch_bounds__(256) void k_cxd(
      const __hip_bfloat16* __restrict__ bxb,   // [N,256] pre-conv x
      const __hip_bfloat16* __restrict__ xpwt,  // [48,256] x_proj^T (zero-padded)
      const float* __restrict__ cw, const float* __restrict__ cb,
      const float* __restrict__ dtw, const float* __restrict__ dtb,
      unsigned* __restrict__ dxb,               // [N,256] (delta | x) bf16 pair
      float* __restrict__ Bm, float* __restrict__ Cm,
      const unsigned* __restrict__ fb16u, const int* __restrict__ ridx,
      const float* __restrict__ gd, const float* __restrict__ g,
      const float* __restrict__ b, unsigned* __restrict__ catB){
  int tid = threadIdx.x;
  int bid = blockIdx.x;

  if (bid >= NCXB){
    // ---- gather + LN -> catB (bf16 feat rows: half the bytes per gather) ----
    int row = (bid - NCXB)*4 + (tid>>6);
    int lane = tid & 63;
    float ax=0.f, ay=0.f;
    #pragma unroll 4
    for (int k=0;k<16;k++){
      int idx = ridx[row*16+k];
      float ww = gd[row*16+k];
      unsigned fu = fb16u[(size_t)idx*64 + lane];
      ax += ww*bfu2f((unsigned short)(fu & 0xffff));
      ay += ww*bfu2f((unsigned short)(fu >> 16));
    }
    float m = waveRed64(ax+ay) * (1.f/128.f);
    float dx = ax-m, dy = ay-m;
    float var = waveRed64(dx*dx+dy*dy) * (1.f/128.f);
    float is = rsqrtf(var + 1e-5f);
    float2 gg = ((const float2*)g)[lane];
    float2 bb = ((const float2*)b)[lane];
    float ox = dx*is*gg.x + bb.x, oy = dy*is*gg.y + bb.y;
    catB[row*64 + lane] = f2bfu(ox) | (f2bfu(oy) << 16);
    return;
  }

  __shared__ __align__(16) __hip_bfloat16 Xs[CXT][XPAD];  // 8.4 KB
  __shared__ __align__(16) float DT[CXT][8];              // 0.5 KB
  int wave = tid>>6, lane = tid&63;
  int lane16 = lane&15, quad = lane>>4;
  int r0 = bid*CXT;

  // ---- causal depthwise conv + silu direct from global (coalesced rows), write Xs once ----
  {
    int d = tid;
    float cw0=cw[d*4], cw1=cw[d*4+1], cw2=cw[d*4+2], cw3=cw[d*4+3], cbb=cb[d];
    float a_0 = (r0 >= 3) ? __bfloat162float(bxb[(size_t)(r0-3)*256 + d]) : 0.f;
    float a_1 = (r0 >= 2) ? __bfloat162float(bxb[(size_t)(r0-2)*256 + d]) : 0.f;
    float a_2 = (r0 >= 1) ? __bfloat162float(bxb[(size_t)(r0-1)*256 + d]) : 0.f;
    #pragma unroll 4
    for (int t=0;t<CXT;t++){
      float a_3 = __bfloat162float(bxb[(size_t)(r0+t)*256 + d]);
      float xc = siluf_(cbb + cw0*a_0 + cw1*a_1 + cw2*a_2 + cw3*a_3);
      Xs[t][d] = __float2bfloat16(xc);
      a_0=a_1; a_1=a_2; a_2=a_3;
    }
  }
  __syncthreads();

  // ---- xproj MFMA from LDS: dbc[16,48] = xc @ xpwt^T (waves 0..2, one n-tile each) ----
  if (wave < 3){
    f32x4 acc3 = (f32x4){0.f,0.f,0.f,0.f};
    const __hip_bfloat16* Arow = &Xs[lane16][0] + quad*8;
    const __hip_bfloat16* Bb = xpwt + (size_t)(wave*16 + lane16)*256 + quad*8;
    #pragma unroll
    for (int kk=0; kk<256; kk+=32){
      short8 a  = *(const short8*)(Arow + kk);
      short8 bfr = *(const short8*)(Bb + kk);
      acc3 = __builtin_amdgcn_mfma_f32_16x16x32_bf16(a, bfr, acc3, 0, 0, 0);
    }
    int n = wave*16 + lane16;
    #pragma unroll
    for (int r=0;r<4;r++){
      int m = quad*4 + r;
      float v = acc3[r];
      if (n < 8)       DT[m][n] = v;
      else if (n < 24) Bm[(size_t)(r0+m)*16 + (n-8)] = v;
      else if (n < 40) Cm[(size_t)(r0+m)*16 + (n-24)] = v;
    }
  }
  __syncthreads();

  // ---- delta = softplus(dtb + dt8 . dtw[:,d]); pack (delta|x) -> dxb ----
  {
    int d = tid;
    float w8[8];
    #pragma unroll
    for (int j=0;j<8;j++) w8[j] = dtw[j*256+d];
    float dbias = dtb[d];
    #pragma unroll
    for (int t=0;t<CXT;t++){
      const float4* T = (const float4*)&DT[t][0];   // wave-uniform broadcast
      float4 u = T[0], v = T[1];
      float acc = dbias
        + u.x*w8[0] + u.y*w8[1] + u.z*w8[2] + u.w*w8[3]
        + v.x*w8[4] + v.y*w8[5] + v.z*w8[6] + v.w*w8[7];
      float dv = softplusf_(acc);
      unsigned xu = *(const unsigned short*)&Xs[t][d];
      dxb[(size_t)(r0+t)*256 + d] = f2bfu(dv) | (xu << 16);
    }
  }
}

// ---------- K5: scan pass 1 — 256-thread block per chunk (LC=32), dxb=(delta|x) ----------
__global__ __launch_bounds__(256) void k_scan1(const unsigned* __restrict__ dxb,
      const float* __restrict__ Bm, const float* __restrict__ A_log,
      float* __restrict__ dsum_o, __hip_bfloat16* __restrict__ Hc){
  __shared__ float Bl[LC][16];
  int g = blockIdx.x;
  int tid = threadIdx.x;
  int d = tid;
  int t0 = g*LC;
  if (tid < LC*4) ((float4*)&Bl[0][0])[tid] = ((const float4*)(Bm + (size_t)t0*16))[tid];
  __syncthreads();
  float aS[16];
  #pragma unroll
  for (int s=0;s<16;s++) aS[s] = -__expf(A_log[d*16+s]);
  bool fastA = check_intA(aS);
  float h[16] = {};
  float dsum = 0.f;
  if (fastA){
    #pragma unroll 4
    for (int t=0;t<LC;t++){
      unsigned u = dxb[(size_t)(t0+t)*256 + d];
      float dv = bfu2f((unsigned short)(u & 0xffff));
      float xv = bfu2f((unsigned short)(u >> 16));
      const float4* Bp = (const float4*)&Bl[t][0];
      float4 b0=Bp[0], b1=Bp[1], b2=Bp[2], b3=Bp[3];
      float bl[16] = {b0.x,b0.y,b0.z,b0.w, b1.x,b1.y,b1.z,b1.w,
                      b2.x,b2.y,b2.z,b2.w, b3.x,b3.y,b3.z,b3.w};
      dsum += dv;
      float dx_ = dv*xv;
      float w[16]; pow_chain(__expf(-dv), w);
      #pragma unroll
      for (int s=0;s<16;s++) h[s] = w[s]*h[s] + dx_*bl[s];
    }
  } else {
    #pragma unroll 4
    for (int t=0;t<LC;t++){
      unsigned u = dxb[(size_t)(t0+t)*256 + d];
      float dv = bfu2f((unsigned short)(u & 0xffff));
      float xv = bfu2f((unsigned short)(u >> 16));
      const float4* Bp = (const float4*)&Bl[t][0];
      float4 b0=Bp[0], b1=Bp[1], b2=Bp[2], b3=Bp[3];
      float bl[16] = {b0.x,b0.y,b0.z,b0.w, b1.x,b1.y,b1.z,b1.w,
                      b2.x,b2.y,b2.z,b2.w, b3.x,b3.y,b3.z,b3.w};
      dsum += dv;
      float dx_ = dv*xv;
      #pragma unroll
      for (int s=0;s<16;s++) h[s] = __expf(dv*aS[s])*h[s] + dx_*bl[s];
    }
  }
  dsum_o[(size_t)g*256 + d] = dsum;
  unsigned u[8];
  #pragma unroll
  for (int q=0;q<8;q++) u[q] = f2bfu(h[2*q]) | (f2bfu(h[2*q+1]) << 16);
  uint4* Hd = (uint4*)(Hc + (size_t)g*4096 + (size_t)d*16);
  Hd[0] = make_uint4(u[0],u[1],u[2],u[3]);
  Hd[1] = make_uint4(u[4],u[5],u[6],u[7]);
}

// ---------- K6a: within-segment prefix (in place on Hc; dsum prefix to dsum_pre) ----------
__global__ __launch_bounds__(256) void k_carry_a(const float* __restrict__ dsum,
      __hip_bfloat16* __restrict__ Hc, const float* __restrict__ A_log,
      float* __restrict__ dsum_pre, float* __restrict__ segsum, float* __restrict__ Hagg){
  int seg = blockIdx.x;
  int ch  = blockIdx.y*256 + threadIdx.x;
  int d = ch>>4, s = ch&15;
  float aSv = -__expf(A_log[ch]);
  float dpre = 0.f, c = 0.f;
  int g0 = seg*SEGLEN;
  #pragma unroll 4
  for (int i=0;i<SEGLEN;i++){
    int g = g0+i;
    float ds = dsum[(size_t)g*256 + d];
    size_t a = (size_t)g*4096 + ch;
    float hh = __bfloat162float(Hc[a]);
    float p = __expf(ds*aSv);
    if (s==0) dsum_pre[(size_t)g*256 + d] = dpre;
    Hc[a] = __float2bfloat16(c);
    dpre += ds;
    c = p*c + hh;
  }
  if (s==0) segsum[seg*256 + d] = dpre;
  Hagg[(size_t)seg*4096 + ch] = c;
}

// ---------- K6b: scan over segment aggregates -> Cseg ----------
__global__ __launch_bounds__(256) void k_carry_b(const float* __restrict__ segsum,
      const float* __restrict__ Hagg, const float* __restrict__ A_log,
      float* __restrict__ Cseg){
  int ch = blockIdx.x*256 + threadIdx.x;
  int d = ch>>4;
  float aSv = -__expf(A_log[ch]);
  float c = 0.f;
  #pragma unroll 8
  for (int s=0;s<NSEG;s++){
    Cseg[(size_t)s*4096 + ch] = c;
    c = __expf(segsum[s*256 + d]*aSv)*c + Hagg[(size_t)s*4096 + ch];
  }
}

// ---------- K7: scan pass 2 — 256-thread block per chunk (LC=32), gated y ----------
__global__ __launch_bounds__(256) void k_scan2(const unsigned* __restrict__ dxb,
      const __hip_bfloat16* __restrict__ zb, const float* __restrict__ Bm,
      const float* __restrict__ Cm, const float* __restrict__ A_log,
      const float* __restrict__ Dp, const float* __restrict__ dsum_pre,
      const __hip_bfloat16* __restrict__ Hc, const float* __restrict__ Cseg,
      __hip_bfloat16* __restrict__ yb){
  __shared__ float Bl[LC][16];
  __shared__ float Cl[LC][16];
  int g = blockIdx.x;
  int tid = threadIdx.x;
  int d = tid;
  int t0 = g*LC;
  if (tid < 128) ((float4*)&Bl[0][0])[tid] = ((const float4*)(Bm + (size_t)t0*16))[tid];
  else ((float4*)&Cl[0][0])[tid-128] = ((const float4*)(Cm + (size_t)t0*16))[tid-128];
  __syncthreads();
  int seg = g / SEGLEN;
  float aS[16];
  #pragma unroll
  for (int s=0;s<16;s++) aS[s] = -__expf(A_log[d*16+s]);
  bool fastA = check_intA(aS);
  float h[16];
  {
    float dpre = dsum_pre[(size_t)g*256 + d];
    const uint4* hp = (const uint4*)(Hc + (size_t)g*4096 + (size_t)d*16);
    uint4 H0 = hp[0], H1 = hp[1];
    unsigned hu[8] = {H0.x,H0.y,H0.z,H0.w, H1.x,H1.y,H1.z,H1.w};
    const float4* cs = (const float4*)(Cseg + (size_t)seg*4096 + (size_t)d*16);
    float ws[16];
    if (fastA){
      pow_chain(__expf(-dpre), ws);
    } else {
      #pragma unroll
      for (int s=0;s<16;s++) ws[s] = __expf(dpre*aS[s]);
    }
    #pragma unroll
    for (int q=0;q<4;q++){
      float4 C = cs[q];
      h[q*4+0] = ws[q*4+0]*C.x + bfu2f((unsigned short)(hu[q*2]   & 0xffff));
      h[q*4+1] = ws[q*4+1]*C.y + bfu2f((unsigned short)(hu[q*2]   >> 16));
      h[q*4+2] = ws[q*4+2]*C.z + bfu2f((unsigned short)(hu[q*2+1] & 0xffff));
      h[q*4+3] = ws[q*4+3]*C.w + bfu2f((unsigned short)(hu[q*2+1] >> 16));
    }
  }
  float dpar = Dp[d];
  if (fastA){
    #pragma unroll 4
    for (int t=0;t<LC;t++){
      unsigned u = dxb[(size_t)(t0+t)*256 + d];
      float dv = bfu2f((unsigned short)(u & 0xffff));
      float xv = bfu2f((unsigned short)(u >> 16));
      float zv = __bfloat162float(zb[(size_t)(t0+t)*256 + d]);
      const float4* Bp = (const float4*)&Bl[t][0];
      const float4* Cp = (const float4*)&Cl[t][0];
      float4 b0=Bp[0], b1=Bp[1], b2=Bp[2], b3=Bp[3];
      float4 c0=Cp[0], c1=Cp[1], c2=Cp[2], c3=Cp[3];
      float bl[16] = {b0.x,b0.y,b0.z,b0.w, b1.x,b1.y,b1.z,b1.w,
                      b2.x,b2.y,b2.z,b2.w, b3.x,b3.y,b3.z,b3.w};
      float cl[16] = {c0.x,c0.y,c0.z,c0.w, c1.x,c1.y,c1.z,c1.w,
                      c2.x,c2.y,c2.z,c2.w, c3.x,c3.y,c3.z,c3.w};
      float dx_ = dv*xv;
      float w[16]; pow_chain(__expf(-dv), w);
      float yv = 0.f;
      #pragma unroll
      for (int s=0;s<16;s++){
        h[s] = w[s]*h[s] + dx_*bl[s];
        yv += h[s]*cl[s];
      }
      yb[(size_t)(t0+t)*256 + d] = __float2bfloat16((yv + dpar*xv)*zv);
    }
  } else {
    #pragma unroll 4
    for (int t=0;t<LC;t++){
      unsigned u = dxb[(size_t)(t0+t)*256 + d];
      float dv = bfu2f((unsigned short)(u & 0xffff));
      float xv = bfu2f((unsigned short)(u >> 16));
      float zv = __bfloat162float(zb[(size_t)(t0+t)*256 + d]);
      const float4* Bp = (const float4*)&Bl[t][0];
      const float4* Cp = (const float4*)&Cl[t][0];
      float4 b0=Bp[0], b1=Bp[1], b2=Bp[2], b3=Bp[3];
      float4 c0=Cp[0], c1=Cp[1], c2=Cp[2], c3=Cp[3];
      float bl[16] = {b0.x,b0.y,b0.z,b0.w, b1.x,b1.y,b1.z,b1.w,
                      b2.x,b2.y,b2.z,b2.w, b3.x,b3.y,b3.z,b3.w};
      float cl[16] = {c0.x,c0.y,c0.z,c0.w, c1.x,c1.y,c1.z,c1.w,
                      c2.x,c2.y,c2.z,c2.w, c3.x,c3.y,c3.z,c3.w};
      float dx_ = dv*xv;
      float yv = 0.f;
      #pragma unroll
      for (int s=0;s<16;s++){
        h[s] = __expf(dv*aS[s])*h[s] + dx_*bl[s];
        yv += h[s]*cl[s];
      }
      yb[(size_t)(t0+t)*256 + d] = __float2bfloat16((yv + dpar*xv)*zv);
    }
  }
}

// ---------- K_tail: out_proj+LN -> mlp1+LN+relu -> mlp2, all in one block (64 rows) ----------
__global__ __launch_bounds__(256) void k_tail(const __hip_bfloat16* __restrict__ yb,
      const __hip_bfloat16* __restrict__ opwt, const float* __restrict__ feat,
      const float* __restrict__ lng, const float* __restrict__ lnb,
      const unsigned* __restrict__ catB,
      const __hip_bfloat16* __restrict__ w1t, const float* __restrict__ b1,
      const float* __restrict__ lag, const float* __restrict__ lab,
      const __hip_bfloat16* __restrict__ w2t, const float* __restrict__ b2,
      float* __restrict__ out){
  __shared__ __align__(16) float Ls[64][132];
  __shared__ __align__(16) unsigned Cu[64][132];  // bf16-pair tile: cat (256 wide) then h1 (128 wide)
  int tid = threadIdx.x;
  int wave = tid>>6, lane = tid&63;
  int wm = wave>>1, wn = wave&1;
  int lane16 = lane&15, quad = lane>>4;
  int r0 = blockIdx.x*64;

  // stage gathered half of cat into Cu cols 64..127 (bf16 cols 128..255)
  #pragma unroll
  for (int i=0;i<16;i++){
    int idx = i*256 + tid;
    int row = idx>>6, c = idx&63;
    Cu[row][64+c] = catB[(size_t)(r0+row)*64 + c];
  }

  f32x4 acc[2][4];
  // ---- GEMM1: yb[64x256] @ opwt[128x256]^T, + feat resid -> Ls ----
  #pragma unroll
  for (int i=0;i<2;i++)
    #pragma unroll
    for (int j=0;j<4;j++) acc[i][j] = (f32x4){0.f,0.f,0.f,0.f};
  {
    const __hip_bfloat16* Ab = yb   + (size_t)(r0 + wm*32 + lane16)*256 + quad*8;
    const __hip_bfloat16* Bb = opwt + (size_t)(wn*64 + lane16)*256 + quad*8;
    #pragma unroll 2
    for (int kk=0; kk<256; kk+=32){
      short8 a[2], bf[4];
      #pragma unroll
      for (int i=0;i<2;i++) a[i] = *(const short8*)(Ab + (size_t)i*16*256 + kk);
      #pragma unroll
      for (int j=0;j<4;j++) bf[j] = *(const short8*)(Bb + (size_t)j*16*256 + kk);
      #pragma unroll
      for (int i=0;i<2;i++)
        #pragma unroll
        for (int j=0;j<4;j++)
          acc[i][j] = __builtin_amdgcn_mfma_f32_16x16x32_bf16(a[i], bf[j], acc[i][j], 0, 0, 0);
    }
  }
  #pragma unroll
  for (int i=0;i<2;i++)
    #pragma unroll
    for (int j=0;j<4;j++){
      int n = wn*64 + j*16 + lane16;
      #pragma unroll
      for (int r=0;r<4;r++){
        int m = wm*32 + i*16 + quad*4 + r;
        Ls[m][n] = acc[i][j][r] + feat[(size_t)(r0+m)*128 + n];
      }
    }
  __syncthreads();
  // ---- LN1 -> Cu cols 0..63 (bf16 cols 0..127) ----
  {
    float2 gv = ((const float2*)lng)[lane];
    float2 bv = ((const float2*)lnb)[lane];
    #pragma unroll 4
    for (int rr=0; rr<16; rr++){
      int row = wave*16 + rr;
      float2 v = *(const float2*)&Ls[row][2*lane];
      float mm = waveRed64(v.x+v.y) * (1.f/128.f);
      float dx = v.x-mm, dy = v.y-mm;
      float var = waveRed64(dx*dx+dy*dy) * (1.f/128.f);
      float is = rsqrtf(var + 1e-5f);
      Cu[row][lane] = f2bfu(dx*is*gv.x + bv.x) | (f2bfu(dy*is*gv.y + bv.y) << 16);
    }
  }
  __syncthreads();
  // ---- GEMM2: cat[64x256] (LDS) @ w1t[128x256]^T, + b1 -> Ls ----
  #pragma unroll
  for (int i=0;i<2;i++)
    #pragma unroll
    for (int j=0;j<4;j++) acc[i][j] = (f32x4){0.f,0.f,0.f,0.f};
  {
    const __hip_bfloat16* Bb = w1t + (size_t)(wn*64 + lane16)*256 + quad*8;
    #pragma unroll 2
    for (int kk=0; kk<256; kk+=32){
      short8 a[2], bf[4];
      #pragma unroll
      for (int i=0;i<2;i++)
        a[i] = *(const short8*)(&Cu[wm*32 + i*16 + lane16][0] + (kk>>1) + quad*4);
      #pragma unroll
      for (int j=0;j<4;j++) bf[j] = *(const short8*)(Bb + (size_t)j*16*256 + kk);
      #pragma unroll
      for (int i=0;i<2;i++)
        #pragma unroll
        for (int j=0;j<4;j++)
          acc[i][j] = __builtin_amdgcn_mfma_f32_16x16x32_bf16(a[i], bf[j], acc[i][j], 0, 0, 0);
    }
  }
  #pragma unroll
  for (int i=0;i<2;i++)
    #pragma unroll
    for (int j=0;j<4;j++){
      int n = wn*64 + j*16 + lane16;
      float bv1 = b1[n];
      #pragma unroll
      for (int r=0;r<4;r++){
        int m = wm*32 + i*16 + quad*4 + r;
        Ls[m][n] = acc[i][j][r] + bv1;
      }
    }
  __syncthreads();
  // ---- LN2 + relu -> Cu cols 0..63 (h1, bf16 cols 0..127) ----
  {
    float2 gv = ((const float2*)lag)[lane];
    float2 bv = ((const float2*)lab)[lane];
    #pragma unroll 4
    for (int rr=0; rr<16; rr++){
      int row = wave*16 + rr;
      float2 v = *(const float2*)&Ls[row][2*lane];
      float mm = waveRed64(v.x+v.y) * (1.f/128.f);
      float dx = v.x-mm, dy = v.y-mm;
      float var = waveRed64(dx*dx+dy*dy) * (1.f/128.f);
      float is = rsqrtf(var + 1e-5f);
      float ox = fmaxf(dx*is*gv.x + bv.x, 0.f);
      float oy = fmaxf(dy*is*gv.y + bv.y, 0.f);
      Cu[row][lane] = f2bfu(ox) | (f2bfu(oy) << 16);
    }
  }
  __syncthreads();
  // ---- GEMM3 (operand-swapped): h1[64x128] (LDS) @ w2t[128x128]^T, + b2 -> out (float4) ----
  #pragma unroll
  for (int i=0;i<2;i++)
    #pragma unroll
    for (int j=0;j<4;j++) acc[i][j] = (f32x4){0.f,0.f,0.f,0.f};
  {
    const __hip_bfloat16* Bb = w2t + (size_t)(wn*64 + lane16)*128 + quad*8;
    #pragma unroll
    for (int kk=0; kk<128; kk+=32){
      short8 a[2], bf[4];
      #pragma unroll
      for (int i=0;i<2;i++)
        a[i] = *(const short8*)(&Cu[wm*32 + i*16 + lane16][0] + (kk>>1) + quad*4);
      #pragma unroll
      for (int j=0;j<4;j++) bf[j] = *(const short8*)(Bb + (size_t)j*16*128 + kk);
      #pragma unroll
      for (int i=0;i<2;i++)
        #pragma unroll
        for (int j=0;j<4;j++)
          acc[i][j] = __builtin_amdgcn_mfma_f32_16x16x32_bf16(bf[j], a[i], acc[i][j], 0, 0, 0);
    }
  }
  #pragma unroll
  for (int i=0;i<2;i++){
    int m = wm*32 + i*16 + lane16;
    #pragma unroll
    for (int j=0;j<4;j++){
      int n0 = wn*64 + j*16 + quad*4;
      float4 o;
      o.x = acc[i][j][0] + b2[n0+0];
      o.y = acc[i][j][1] + b2[n0+1];
      o.z = acc[i][j][2] + b2[n0+2];
      o.w = acc[i][j][3] + b2[n0+3];
      *(float4*)(out + (size_t)(r0+m)*128 + n0) = o;
    }
  }
}

extern "C" void kernel_launch(void* const* d_in, const int* in_sizes, int n_in,
                              void* d_out, int out_size, void* d_ws, size_t ws_size,
                              hipStream_t stream){
  const float* feat = (const float*)d_in[0];
  const int*   ridx = (const int*)d_in[2];
  const float* gd   = (const float*)d_in[3];
  const float* ipw  = (const float*)d_in[5];
  const float* cw   = (const float*)d_in[6];
  const float* cb   = (const float*)d_in[7];
  const float* xpw  = (const float*)d_in[8];
  const float* dtw  = (const float*)d_in[9];
  const float* dtb  = (const float*)d_in[10];
  const float* alog = (const float*)d_in[11];
  const float* dpar = (const float*)d_in[12];
  const float* opw  = (const float*)d_in[13];
  const float* rmsw = (const float*)d_in[14];
  const float* lng  = (const float*)d_in[15];
  const float* lnb  = (const float*)d_in[16];
  const float* w1   = (const float*)d_in[17];
  const float* b1   = (const float*)d_in[18];
  const float* lag  = (const float*)d_in[19];
  const float* lab  = (const float*)d_in[20];
  const float* w2   = (const float*)d_in[21];
  const float* b2   = (const float*)d_in[22];
  float* out = (float*)d_out;

  char* p = (char*)d_ws;
  __hip_bfloat16* bxb  = (__hip_bfloat16*)p; p += (size_t)N_TOK*256*2;   // 16MB pre-conv x
  __hip_bfloat16* zb   = (__hip_bfloat16*)p; p += (size_t)N_TOK*256*2;   // 16MB silu(z)
  unsigned* dxb        = (unsigned*)p;       p += (size_t)N_TOK*256*4;   // 32MB (delta|x) packed
  unsigned* catB       = (unsigned*)p;       p += (size_t)N_TOK*64*4;    // 8MB gathered+LN half
  unsigned* fb16u      = (unsigned*)p;       p += (size_t)N_TOK*64*4;    // 8MB bf16 feat copy
  __hip_bfloat16* yb   = (__hip_bfloat16*)p; p += (size_t)N_TOK*256*2;   // 16MB gated y; a0 early
  float* Bm   = (float*)p; p += (size_t)N_TOK*16*4;                      // 2MB
  float* Cm   = (float*)p; p += (size_t)N_TOK*16*4;                      // 2MB
  __hip_bfloat16* Hc = (__hip_bfloat16*)p; p += (size_t)NCHUNK*4096*2;   // 8MB (bf16)
  float* dsum = (float*)p; p += (size_t)NCHUNK*256*4;                    // 1MB
  float* dpre = (float*)p; p += (size_t)NCHUNK*256*4;                    // 1MB
  float* segs = (float*)p; p += (size_t)NSEG*256*4;                      // 64KB
  float* Hagg = (float*)p; p += (size_t)NSEG*4096*4;                     // 1MB
  float* Cseg = (float*)p; p += (size_t)NSEG*4096*4;                     // 1MB
  __hip_bfloat16* ipwt = (__hip_bfloat16*)p; p += 512*128*2;
  __hip_bfloat16* opwt = (__hip_bfloat16*)p; p += 128*256*2;
  __hip_bfloat16* w1t  = (__hip_bfloat16*)p; p += 128*256*2;
  __hip_bfloat16* w2t  = (__hip_bfloat16*)p; p += 128*128*2;
  __hip_bfloat16* xpwt = (__hip_bfloat16*)p; p += 48*256*2;
  __hip_bfloat16* a0 = yb;                     // N*128 bf16, dead before scan2 writes yb

  hipLaunchKernelGGL(k_front, dim3(8192+624), dim3(256), 0, stream,
                     feat, rmsw, (unsigned*)a0, fb16u,
                     ipw, opw, w1, w2, xpw, ipwt, opwt, w1t, w2t, xpwt);
  hipLaunchKernelGGL((k_mfma<4,4>), dim3(N_TOK/128, 4), dim3(256), 0, stream,
                     a0, ipwt, 128, bxb, zb);
  hipLaunchKernelGGL(k_cxd, dim3(NCXB + 8192), dim3(256), 0, stream,
                     bxb, xpwt, cw, cb, dtw, dtb, dxb, Bm, Cm,
                     fb16u, ridx, gd, lng, lnb, catB);
  hipLaunchKernelGGL(k_scan1, dim3(NCHUNK), dim3(256), 0, stream,
                     dxb, Bm, alog, dsum, Hc);
  hipLaunchKernelGGL(k_carry_a, dim3(NSEG, 16), dim3(256), 0, stream,
                     dsum, Hc, alog, dpre, segs, Hagg);
  hipLaunchKernelGGL(k_carry_b, dim3(16), dim3(256), 0, stream, segs, Hagg, alog, Cseg);
  hipLaunchKernelGGL(k_scan2, dim3(NCHUNK), dim3(256), 0, stream,
                     dxb, zb, Bm, Cm, alog, dpar, dpre, Hc, Cseg, yb);
  hipLaunchKernelGGL(k_tail, dim3(N_TOK/64), dim3(256), 0, stream,
                     yb, opwt, feat, lng, lnb, catB, w1t, b1, lag, lab, w2t, b2, out);
}